// Round 7
// baseline (209.045 us; speedup 1.0000x reference)
//
#include <hip/hip_runtime.h>

// Problem constants (from reference setup_inputs):
//   X:   [B=8, N_old=2048, F=256] fp32
//   A:   [B=8, N_new=4096, N_new=4096] fp32 (pass-through)
//   idx: [B=8, N_old=2048, 1] int32, values in [0, N_new)
// Output: new_X [8,4096,256] fp32 (scatter-add of X rows), then A, concat flat.
//
// Structure (R5, proven 202.6 us): memset(counts) + build inverted index ->
// ONE fused kernel, gather:copy block interleave. R6 change: grid resized to
// 18432 = 2048 gather (every 9th block) + 16384 copy blocks so the A copy is
// EXACTLY 8 vec4-iterations per thread (2^25 / 2^22) — fully unrolled, no
// bounds check, no tail divergence.

typedef float f32x4 __attribute__((ext_vector_type(4)));

constexpr int B_     = 8;
constexpr int N_OLD  = 2048;
constexpr int N_NEW  = 4096;
constexpr int F_     = 256;

constexpr int ROWS_IN   = B_ * N_OLD;                             // 16384
constexpr int ROWS_OUT  = B_ * N_NEW;                             // 32768
constexpr size_t NEWX_ELEMS = (size_t)ROWS_OUT * F_;              // 8,388,608
constexpr size_t A_ELEMS    = (size_t)B_ * N_NEW * (size_t)N_NEW; // 134,217,728
constexpr size_t A_VEC4     = A_ELEMS / 4;                        // 2^25 vec4

constexpr int CAP = 32;                          // bucket cap (exp. max ~7)
constexpr size_t COUNTS_BYTES  = (size_t)ROWS_OUT * sizeof(int);        // 128 KB
constexpr size_t ENTRIES_BYTES = (size_t)ROWS_OUT * CAP * sizeof(int);  // 4 MB
constexpr size_t WS_NEEDED     = COUNTS_BYTES + ENTRIES_BYTES;

constexpr int GATHER_BLOCKS = 2048;              // x16 rows = 32768, exact
constexpr int COPY_BLOCKS   = 16384;
constexpr int TOTAL_BLOCKS  = GATHER_BLOCKS + COPY_BLOCKS;       // 18432
constexpr size_t COPY_STRIDE = (size_t)COPY_BLOCKS * 256;        // 2^22 vec4
constexpr int COPY_ITERS    = (int)(A_VEC4 / COPY_STRIDE);       // 8, exact

// ---- index build (tiny prologue dispatches) -----------------------------------

__global__ void build_index_kernel(const int* __restrict__ idx,
                                   int* __restrict__ counts,
                                   int* __restrict__ entries) {
    const int i = blockIdx.x * blockDim.x + threadIdx.x;   // 0..16383
    const int b = i >> 11;                                  // / N_OLD
    const int bin = (b << 12) + idx[i];                     // b*N_NEW + node
    const int pos = atomicAdd(&counts[bin], 1);
    if (pos < CAP) entries[bin * CAP + pos] = i;            // global X row id
}

// ---- fused: 1:8 interleaved gather / streaming copy ---------------------------

__global__ __launch_bounds__(256) void fused_gather_copy_kernel(
        const f32x4* __restrict__ X4,
        const f32x4* __restrict__ A4,
        const int*   __restrict__ counts,
        const int*   __restrict__ entries,
        f32x4* __restrict__ newX4,
        f32x4* __restrict__ Aout4) {
    const int q = blockIdx.x / 9;          // group id, 0..2047
    const int j = blockIdx.x - q * 9;      // 0..8 within group
    if (j == 0) {
        // gather block: 16 output rows (4 per wave, sequential)
        const int wave = threadIdx.x >> 6;
        const int lane = threadIdx.x & 63;
        #pragma unroll
        for (int r = 0; r < 4; ++r) {
            const int row = q * 16 + wave * 4 + r;     // 0..32767, exact cover
            int c = counts[row];
            if (c > CAP) c = CAP;
            f32x4 acc = (f32x4)(0.f);
            const int* e = &entries[(size_t)row * CAP];
            for (int k = 0; k < c; ++k)
                acc += X4[(size_t)e[k] * 64 + lane];   // coalesced 1 KB row
            __builtin_nontemporal_store(acc, &newX4[(size_t)row * 64 + lane]);
        }
    } else {
        // copy block: exactly 8 vec4 iterations, no bounds check
        const size_t cid = (size_t)q * 8 + (j - 1);    // 0..16383
        size_t i = cid * 256 + threadIdx.x;
        #pragma unroll
        for (int it = 0; it < COPY_ITERS; ++it) {
            const f32x4 v = __builtin_nontemporal_load(&A4[i]);
            __builtin_nontemporal_store(v, &Aout4[i]);
            i += COPY_STRIDE;
        }
    }
}

// ---- fallback (round-0 proven) ------------------------------------------------

__global__ void zero_newx_kernel(float4* __restrict__ p, size_t n4) {
    size_t i = (size_t)blockIdx.x * blockDim.x + threadIdx.x;
    size_t stride = (size_t)gridDim.x * blockDim.x;
    const float4 z = make_float4(0.f, 0.f, 0.f, 0.f);
    for (; i < n4; i += stride) p[i] = z;
}

__global__ void scatter_add_kernel(const float* __restrict__ X,
                                   const int* __restrict__ idx,
                                   float* __restrict__ out) {
    const int row = blockIdx.x;
    const int f   = threadIdx.x;
    const int b   = row / N_OLD;
    const int node = idx[row];
    const float v = X[(size_t)row * F_ + f];
    atomicAdd(&out[((size_t)b * N_NEW + node) * (size_t)F_ + f], v);
}

extern "C" void kernel_launch(void* const* d_in, const int* in_sizes, int n_in,
                              void* d_out, int out_size, void* d_ws, size_t ws_size,
                              hipStream_t stream) {
    const float* X   = (const float*)d_in[0];
    const float* A   = (const float*)d_in[1];
    const int*   idx = (const int*)d_in[2];

    float* newX  = (float*)d_out;
    float* A_out = (float*)d_out + NEWX_ELEMS;

    if (ws_size >= WS_NEEDED) {
        int* counts  = (int*)d_ws;
        int* entries = (int*)((char*)d_ws + COUNTS_BYTES);

        // counts must be zero every call (graph replays; ws poisoned once)
        (void)hipMemsetAsync(counts, 0, COUNTS_BYTES, stream);

        build_index_kernel<<<ROWS_IN / 256, 256, 0, stream>>>(idx, counts, entries);

        fused_gather_copy_kernel<<<TOTAL_BLOCKS, 256, 0, stream>>>(
            (const f32x4*)X, (const f32x4*)A, counts, entries,
            (f32x4*)newX, (f32x4*)A_out);
    } else {
        zero_newx_kernel<<<2048, 256, 0, stream>>>((float4*)newX, NEWX_ELEMS / 4);
        scatter_add_kernel<<<ROWS_IN, 256, 0, stream>>>(X, idx, newX);
        (void)hipMemcpyAsync(A_out, A, A_ELEMS * sizeof(float),
                             hipMemcpyDeviceToDevice, stream);
    }
}

// Round 8
// 194.117 us; speedup vs baseline: 1.0769x; 1.0769x over previous
//
#include <hip/hip_runtime.h>

// Problem constants (from reference setup_inputs):
//   X:   [B=8, N_old=2048, F=256] fp32
//   A:   [B=8, N_new=4096, N_new=4096] fp32 (pass-through)
//   idx: [B=8, N_old=2048, 1] int32, values in [0, N_new)
// Output: new_X [8,4096,256] fp32 (scatter-add of X rows), then A, concat flat.
//
// R7: SINGLE dispatch. R5's proven geometry (16384 blocks, every 8th block
// gathers 16 output rows, the rest stream the A copy) with the inverted index
// replaced by a per-block LDS scan: each gather block loads its batch's idx
// slice (8 KB) into LDS once, then each wave ballot-scans for its 4 rows.
// No memset, no build kernel, no workspace, no index traffic.

typedef float f32x4 __attribute__((ext_vector_type(4)));

constexpr int B_     = 8;
constexpr int N_OLD  = 2048;
constexpr int N_NEW  = 4096;
constexpr int F_     = 256;

constexpr int ROWS_OUT  = B_ * N_NEW;                             // 32768
constexpr size_t NEWX_ELEMS = (size_t)ROWS_OUT * F_;              // 8,388,608
constexpr size_t A_ELEMS    = (size_t)B_ * N_NEW * (size_t)N_NEW; // 134,217,728
constexpr size_t A_VEC4     = A_ELEMS / 4;                        // 2^25 vec4

constexpr int TOTAL_BLOCKS  = 16384;             // R5 geometry, proven 202.6 us
constexpr int COPY_BLOCKS   = TOTAL_BLOCKS - TOTAL_BLOCKS / 8;   // 14336
constexpr size_t COPY_STRIDE = (size_t)COPY_BLOCKS * 256;        // 3,670,016

__global__ __launch_bounds__(256) void fused_unpool_kernel(
        const f32x4* __restrict__ X4,
        const f32x4* __restrict__ A4,
        const int*   __restrict__ idx,
        f32x4* __restrict__ newX4,
        f32x4* __restrict__ Aout4) {
    __shared__ int sidx[N_OLD];                     // 8 KB
    const int j = blockIdx.x & 7;
    if (j == 0) {
        // ---- gather block: 16 output rows, all in batch gid/256 ------------
        const int gid  = blockIdx.x >> 3;           // 0..2047
        const int b    = gid >> 8;                  // gid*16/4096: batch id
        const int wave = threadIdx.x >> 6;
        const int lane = threadIdx.x & 63;

        // stage this batch's idx slice (8 KB, coalesced, L2-resident)
        const int* __restrict__ idxb = idx + b * N_OLD;
        #pragma unroll
        for (int t = 0; t < N_OLD / 256; ++t)
            sidx[t * 256 + threadIdx.x] = idxb[t * 256 + threadIdx.x];
        __syncthreads();                            // block-uniform branch: safe

        #pragma unroll
        for (int r = 0; r < 4; ++r) {
            const int row  = gid * 16 + wave * 4 + r;   // 0..32767, exact cover
            const int node = row & (N_NEW - 1);
            f32x4 acc = (f32x4)(0.f);
            for (int t = 0; t < N_OLD / 64; ++t) {      // 32 LDS iters
                const int v = sidx[t * 64 + lane];      // 2-way bank alias: free
                unsigned long long m = __ballot(v == node);
                while (m) {                             // expected ~0.5 pops/row
                    const int k = __builtin_ctzll(m);
                    m &= m - 1;
                    const int src = b * N_OLD + t * 64 + k;
                    acc += X4[(size_t)src * 64 + lane]; // coalesced 1 KB row
                }
            }
            __builtin_nontemporal_store(acc, &newX4[(size_t)row * 64 + lane]);
        }
    } else {
        // ---- copy block: R5's proven streaming loop ------------------------
        const size_t cid = (size_t)(blockIdx.x >> 3) * 7 + (j - 1); // 0..14335
        size_t i = cid * 256 + threadIdx.x;
        #pragma unroll 2
        for (; i < A_VEC4; i += COPY_STRIDE) {
            const f32x4 v = __builtin_nontemporal_load(&A4[i]);
            __builtin_nontemporal_store(v, &Aout4[i]);
        }
    }
}

extern "C" void kernel_launch(void* const* d_in, const int* in_sizes, int n_in,
                              void* d_out, int out_size, void* d_ws, size_t ws_size,
                              hipStream_t stream) {
    const f32x4* X4 = (const f32x4*)d_in[0];
    const f32x4* A4 = (const f32x4*)d_in[1];
    const int*  idx = (const int*)d_in[2];

    f32x4* newX4 = (f32x4*)d_out;
    f32x4* Aout4 = (f32x4*)((float*)d_out + NEWX_ELEMS);

    fused_unpool_kernel<<<TOTAL_BLOCKS, 256, 0, stream>>>(X4, A4, idx, newX4, Aout4);
}

// Round 9
// 193.831 us; speedup vs baseline: 1.0785x; 1.0015x over previous
//
#include <hip/hip_runtime.h>

// Problem constants (from reference setup_inputs):
//   X:   [B=8, N_old=2048, F=256] fp32
//   A:   [B=8, N_new=4096, N_new=4096] fp32 (pass-through)
//   idx: [B=8, N_old=2048, 1] int32, values in [0, N_new)
// Output: new_X [8,4096,256] fp32 (scatter-add of X rows), then A, concat flat.
//
// R8 = R7 structure (single dispatch, 16384 blocks, every 8th gathers via an
// LDS scan of its batch's idx slice, rest stream the A copy) with:
//   - copy loop: explicit 2-deep pairing (2 independent nt-loads issued before
//     the dependent stores) to double per-thread load MLP
//   - gather: ONE LDS pass per wave with 4 node-compares per element
//     (replaces 4 passes; halves scan VALU/LDS work)

typedef float f32x4 __attribute__((ext_vector_type(4)));

constexpr int B_     = 8;
constexpr int N_OLD  = 2048;
constexpr int N_NEW  = 4096;
constexpr int F_     = 256;

constexpr int ROWS_OUT  = B_ * N_NEW;                             // 32768
constexpr size_t NEWX_ELEMS = (size_t)ROWS_OUT * F_;              // 8,388,608
constexpr size_t A_ELEMS    = (size_t)B_ * N_NEW * (size_t)N_NEW; // 134,217,728
constexpr size_t A_VEC4     = A_ELEMS / 4;                        // 2^25 vec4

constexpr int TOTAL_BLOCKS  = 16384;             // R5/R7 proven geometry
constexpr int COPY_BLOCKS   = TOTAL_BLOCKS - TOTAL_BLOCKS / 8;   // 14336
constexpr size_t COPY_STRIDE = (size_t)COPY_BLOCKS * 256;        // 3,670,016

__global__ __launch_bounds__(256) void fused_unpool_kernel(
        const f32x4* __restrict__ X4,
        const f32x4* __restrict__ A4,
        const int*   __restrict__ idx,
        f32x4* __restrict__ newX4,
        f32x4* __restrict__ Aout4) {
    __shared__ int sidx[N_OLD];                     // 8 KB
    const int j = blockIdx.x & 7;
    if (j == 0) {
        // ---- gather block: 16 output rows (4 consecutive nodes per wave) ---
        const int gid  = blockIdx.x >> 3;           // 0..2047
        const int b    = gid >> 8;                  // batch id
        const int wave = threadIdx.x >> 6;
        const int lane = threadIdx.x & 63;

        // stage this batch's idx slice (8 KB, coalesced)
        const int* __restrict__ idxb = idx + b * N_OLD;
        #pragma unroll
        for (int t = 0; t < N_OLD / 256; ++t)
            sidx[t * 256 + threadIdx.x] = idxb[t * 256 + threadIdx.x];
        __syncthreads();                            // block-uniform branch: safe

        const int row0  = gid * 16 + wave * 4;      // first of 4 rows
        const int node0 = row0 & (N_NEW - 1);
        const int xbase = b * N_OLD;
        f32x4 a0 = (f32x4)(0.f), a1 = (f32x4)(0.f);
        f32x4 a2 = (f32x4)(0.f), a3 = (f32x4)(0.f);

        for (int t = 0; t < N_OLD / 64; ++t) {      // ONE pass: 32 LDS iters
            const int d = sidx[t * 64 + lane] - node0;   // match iff d in [0,4)
            unsigned long long m0 = __ballot(d == 0);
            unsigned long long m1 = __ballot(d == 1);
            unsigned long long m2 = __ballot(d == 2);
            unsigned long long m3 = __ballot(d == 3);
            while (m0) { const int k = __builtin_ctzll(m0); m0 &= m0 - 1;
                         a0 += X4[(size_t)(xbase + t * 64 + k) * 64 + lane]; }
            while (m1) { const int k = __builtin_ctzll(m1); m1 &= m1 - 1;
                         a1 += X4[(size_t)(xbase + t * 64 + k) * 64 + lane]; }
            while (m2) { const int k = __builtin_ctzll(m2); m2 &= m2 - 1;
                         a2 += X4[(size_t)(xbase + t * 64 + k) * 64 + lane]; }
            while (m3) { const int k = __builtin_ctzll(m3); m3 &= m3 - 1;
                         a3 += X4[(size_t)(xbase + t * 64 + k) * 64 + lane]; }
        }
        __builtin_nontemporal_store(a0, &newX4[(size_t)(row0 + 0) * 64 + lane]);
        __builtin_nontemporal_store(a1, &newX4[(size_t)(row0 + 1) * 64 + lane]);
        __builtin_nontemporal_store(a2, &newX4[(size_t)(row0 + 2) * 64 + lane]);
        __builtin_nontemporal_store(a3, &newX4[(size_t)(row0 + 3) * 64 + lane]);
    } else {
        // ---- copy block: paired streaming (2 loads in flight per wait) -----
        const size_t cid = (size_t)(blockIdx.x >> 3) * 7 + (j - 1); // 0..14335
        size_t i = cid * 256 + threadIdx.x;
        while (i + COPY_STRIDE < A_VEC4) {
            const f32x4 v0 = __builtin_nontemporal_load(&A4[i]);
            const f32x4 v1 = __builtin_nontemporal_load(&A4[i + COPY_STRIDE]);
            __builtin_nontemporal_store(v0, &Aout4[i]);
            __builtin_nontemporal_store(v1, &Aout4[i + COPY_STRIDE]);
            i += 2 * COPY_STRIDE;
        }
        if (i < A_VEC4) {
            const f32x4 v = __builtin_nontemporal_load(&A4[i]);
            __builtin_nontemporal_store(v, &Aout4[i]);
        }
    }
}

extern "C" void kernel_launch(void* const* d_in, const int* in_sizes, int n_in,
                              void* d_out, int out_size, void* d_ws, size_t ws_size,
                              hipStream_t stream) {
    const f32x4* X4 = (const f32x4*)d_in[0];
    const f32x4* A4 = (const f32x4*)d_in[1];
    const int*  idx = (const int*)d_in[2];

    f32x4* newX4 = (f32x4*)d_out;
    f32x4* Aout4 = (f32x4*)((float*)d_out + NEWX_ELEMS);

    fused_unpool_kernel<<<TOTAL_BLOCKS, 256, 0, stream>>>(X4, A4, idx, newX4, Aout4);
}